// Round 2
// baseline (122.148 us; speedup 1.0000x reference)
//
#include <hip/hip_runtime.h>

#define NIMG   16
#define NA     25200
#define NCH    85
#define NCLS   80
#define CAP    2048          // per-image candidate capacity (~236 expected)
#define TOPK_N 300
#define CONF_T 0.25f
#define IOU_T  0.45f

#define FBLK   256           // filter kernel block size
#define NBLK   512           // nms kernel block size
#define NWORDS 5             // ceil(300/64)

// ---------------- Stage 1: gather filter + compact ----------------
// One thread per anchor. Early exits mean most threads read only 1-2 floats
// (obj, p0) from the row's first cache line; the class scan proceeds in
// chunks of 8 independent loads (same line -> L1 hits) with strict-> exit
// that exactly reproduces first-index argmax semantics on rounded obj*p_j.
__global__ __launch_bounds__(FBLK) void filter_kernel(
    const float* __restrict__ pred, int* __restrict__ cnt,
    unsigned long long* __restrict__ keys)
{
    int a = blockIdx.x * FBLK + threadIdx.x;
    if (a >= NA) return;
    int img = blockIdx.y;
    const float* __restrict__ p = pred + ((size_t)img * NA + a) * NCH;

    float obj = p[4];
    if (obj <= CONF_T) return;                  // ~25% exit: 1 load
    float s0 = obj * p[5];                      // score of class 0 (exact ref rounding)
    if (s0 <= CONF_T) return;                   // ~35% exit: 2 loads, same line

    // argmax==0  <=>  no j>0 with fl(obj*p_j) > s0   (first-index tie-break)
    for (int j0 = 1; j0 < NCLS; j0 += 8) {
        int jn = min(j0 + 8, NCLS);
        float mx = -1.0f;
        #pragma unroll
        for (int j = j0; j < j0 + 8; ++j) {
            if (j < jn) {
                float s = obj * p[5 + j];       // per-element rounded, as reference
                mx = fmaxf(mx, s);
            }
        }
        if (mx > s0) return;                    // some class beats class 0
    }

    int pos = atomicAdd(&cnt[img], 1);
    if (pos < CAP) {
        unsigned cb = __float_as_uint(s0);      // s0 > 0.25 > 0: bits order-preserving
        // key: conf desc, then index asc on ties (matches lax.top_k order)
        keys[(size_t)img * CAP + pos] =
            ((unsigned long long)cb << 32) | (unsigned long long)(0xFFFFFFFFu - (unsigned)a);
    }
}

// ---------------- Stage 2: sort + NMS + mean ----------------
__global__ __launch_bounds__(NBLK) void nms_kernel(
    const float* __restrict__ pred, const int* __restrict__ cnt,
    const unsigned long long* __restrict__ keys_g, float* __restrict__ out)
{
    __shared__ unsigned long long keys[CAP];
    __shared__ float bx1[TOPK_N], by1[TOPK_N], bx2[TOPK_N], by2[TOPK_N], bconf[TOPK_N];
    __shared__ unsigned long long mask[TOPK_N * NWORDS];
    __shared__ unsigned long long keepw[NWORDS];
    __shared__ float rsum[NBLK / 64];
    __shared__ int   rcnt[NBLK / 64];

    int img = blockIdx.x;
    int tid = threadIdx.x;
    int n = min(cnt[img], CAP);

    // ---- bitonic sort (descending) of N = next_pow2(n) keys ----
    int N = 1; while (N < n) N <<= 1;
    for (int i = tid; i < N; i += NBLK)
        keys[i] = (i < n) ? keys_g[(size_t)img * CAP + i] : 0ULL;
    __syncthreads();
    for (int k = 2; k <= N; k <<= 1) {
        for (int j = k >> 1; j > 0; j >>= 1) {
            for (int i = tid; i < N; i += NBLK) {
                int pp = i ^ j;
                if (pp > i) {
                    unsigned long long va = keys[i], vb = keys[pp];
                    bool desc = ((i & k) == 0);
                    if ((va < vb) == desc) { keys[i] = vb; keys[pp] = va; }
                }
            }
            __syncthreads();
        }
    }

    int m = min(n, TOPK_N);

    // ---- gather boxes for the top-m, xywh -> xyxy ----
    if (tid < m) {
        unsigned long long kk = keys[tid];
        unsigned a = 0xFFFFFFFFu - (unsigned)(kk & 0xFFFFFFFFu);
        float conf = __uint_as_float((unsigned)(kk >> 32));
        const float* p = pred + ((size_t)img * NA + a) * NCH;
        float x = p[0], y = p[1], w = p[2], h = p[3];
        bx1[tid] = x - w * 0.5f;
        by1[tid] = y - h * 0.5f;
        bx2[tid] = x + w * 0.5f;
        by2[tid] = y + h * 0.5f;
        bconf[tid] = conf;
    }
    __syncthreads();

    // ---- parallel suppression bit-matrix: word (i,w) covers j in [w*64, w*64+64) ----
    for (int idx = tid; idx < m * NWORDS; idx += NBLK) {
        int i = idx / NWORDS, w = idx % NWORDS;
        unsigned long long bits = 0ULL;
        int jlo = w * 64, jhi = min(jlo + 64, m);
        if (jhi > i + 1) {
            float ax1 = bx1[i], ay1 = by1[i], ax2 = bx2[i], ay2 = by2[i];
            float a1 = (ax2 - ax1) * (ay2 - ay1);
            for (int j = max(jlo, i + 1); j < jhi; ++j) {
                float ltx = fmaxf(ax1, bx1[j]);
                float lty = fmaxf(ay1, by1[j]);
                float rbx = fminf(ax2, bx2[j]);
                float rby = fminf(ay2, by2[j]);
                float ww = fmaxf(rbx - ltx, 0.0f);
                float hh = fmaxf(rby - lty, 0.0f);
                float inter = ww * hh;
                float a2 = (bx2[j] - bx1[j]) * (by2[j] - by1[j]);
                float iou = inter / (a1 + a2 - inter + 1e-9f);  // exact ref op order
                if (iou > IOU_T) bits |= 1ULL << (j - jlo);
            }
        }
        mask[i * NWORDS + w] = bits;
    }
    __syncthreads();

    // ---- serial greedy scan: single wave, bitmask registers, no block syncs ----
    if (tid < 64) {
        int lane = tid;
        unsigned long long kw = 0ULL;
        if (lane < NWORDS) {
            int rem = m - lane * 64;
            kw = (rem >= 64) ? ~0ULL : ((rem <= 0) ? 0ULL : ((1ULL << rem) - 1ULL));
        }
        for (int i = 0; i < m; ++i) {
            unsigned long long wi = __shfl(kw, i >> 6);        // broadcast owner's word
            if ((wi >> (i & 63)) & 1ULL) {                     // keep[i] still alive?
                unsigned long long mw = (lane < NWORDS) ? mask[i * NWORDS + lane] : 0ULL;
                kw &= ~mw;
            }
        }
        if (lane < NWORDS) keepw[lane] = kw;
    }
    __syncthreads();

    // ---- mean of kept confidences ----
    float s = 0.0f; int c = 0;
    if (tid < m) {
        if ((keepw[tid >> 6] >> (tid & 63)) & 1ULL) { s = bconf[tid]; c = 1; }
    }
    for (int off = 32; off > 0; off >>= 1) {
        s += __shfl_down(s, off);
        c += __shfl_down(c, off);
    }
    int wid = tid >> 6;
    if ((tid & 63) == 0) { rsum[wid] = s; rcnt[wid] = c; }
    __syncthreads();
    if (tid == 0) {
        float S = 0.0f; int C = 0;
        for (int wv = 0; wv < NBLK / 64; ++wv) { S += rsum[wv]; C += rcnt[wv]; }
        out[img] = (C > 0) ? S / (float)C : 0.0f;
    }
}

extern "C" void kernel_launch(void* const* d_in, const int* in_sizes, int n_in,
                              void* d_out, int out_size, void* d_ws, size_t ws_size,
                              hipStream_t stream) {
    const float* pred = (const float*)d_in[0];
    float* out = (float*)d_out;

    // ws layout: [0,64)   per-image counters (zeroed each launch)
    //            [256,..) per-image key buffers (16 * 2048 * 8 B = 256 KB)
    int* cnt = (int*)d_ws;
    unsigned long long* keys = (unsigned long long*)((char*)d_ws + 256);

    hipMemsetAsync(d_ws, 0, 256, stream);

    dim3 fgrid((NA + FBLK - 1) / FBLK, NIMG);
    filter_kernel<<<fgrid, FBLK, 0, stream>>>(pred, cnt, keys);
    nms_kernel<<<NIMG, NBLK, 0, stream>>>(pred, cnt, keys, out);
}

// Round 3
// 122.139 us; speedup vs baseline: 1.0001x; 1.0001x over previous
//
#include <hip/hip_runtime.h>

#define NIMG   16
#define NA     25200
#define NCH    85
#define NCLS   80
#define CAP    2048          // per-image candidate capacity (~236 expected)
#define TOPK_N 300
#define CONF_T 0.25f
#define IOU_T  0.45f

#define FBLK   256           // filter kernel block size
#define NBLK   512           // nms kernel block size
#define NWORDS 5             // ceil(300/64)

// ---------------- Stage 0: zero the per-image counters ----------------
// Replaces hipMemsetAsync: a captured memset node cost ~81 us per graph
// replay (rocprof: fillBufferAligned, WRITE_SIZE=0.25KB, dur 81us).
__global__ void zero_cnt_kernel(int* __restrict__ cnt)
{
    if (threadIdx.x < NIMG) cnt[threadIdx.x] = 0;
}

// ---------------- Stage 1: gather filter + compact ----------------
// One thread per anchor. Early exits mean most threads read only 1-2 floats
// (obj, p0) from the row's first cache line; the class scan proceeds in
// chunks of 8 independent loads (same line -> L1 hits) with strict-> exit
// that exactly reproduces first-index argmax semantics on rounded obj*p_j.
__global__ __launch_bounds__(FBLK) void filter_kernel(
    const float* __restrict__ pred, int* __restrict__ cnt,
    unsigned long long* __restrict__ keys)
{
    int a = blockIdx.x * FBLK + threadIdx.x;
    if (a >= NA) return;
    int img = blockIdx.y;
    const float* __restrict__ p = pred + ((size_t)img * NA + a) * NCH;

    float obj = p[4];
    if (obj <= CONF_T) return;                  // ~25% exit: 1 load
    float s0 = obj * p[5];                      // score of class 0 (exact ref rounding)
    if (s0 <= CONF_T) return;                   // ~35% exit: 2 loads, same line

    // argmax==0  <=>  no j>0 with fl(obj*p_j) > s0   (first-index tie-break)
    for (int j0 = 1; j0 < NCLS; j0 += 8) {
        int jn = min(j0 + 8, NCLS);
        float mx = -1.0f;
        #pragma unroll
        for (int j = j0; j < j0 + 8; ++j) {
            if (j < jn) {
                float s = obj * p[5 + j];       // per-element rounded, as reference
                mx = fmaxf(mx, s);
            }
        }
        if (mx > s0) return;                    // some class beats class 0
    }

    int pos = atomicAdd(&cnt[img], 1);
    if (pos < CAP) {
        unsigned cb = __float_as_uint(s0);      // s0 > 0.25 > 0: bits order-preserving
        // key: conf desc, then index asc on ties (matches lax.top_k order)
        keys[(size_t)img * CAP + pos] =
            ((unsigned long long)cb << 32) | (unsigned long long)(0xFFFFFFFFu - (unsigned)a);
    }
}

// ---------------- Stage 2: sort + NMS + mean ----------------
__global__ __launch_bounds__(NBLK) void nms_kernel(
    const float* __restrict__ pred, const int* __restrict__ cnt,
    const unsigned long long* __restrict__ keys_g, float* __restrict__ out)
{
    __shared__ unsigned long long keys[CAP];
    __shared__ float bx1[TOPK_N], by1[TOPK_N], bx2[TOPK_N], by2[TOPK_N], bconf[TOPK_N];
    __shared__ unsigned long long mask[TOPK_N * NWORDS];
    __shared__ unsigned long long keepw[NWORDS];
    __shared__ float rsum[NBLK / 64];
    __shared__ int   rcnt[NBLK / 64];

    int img = blockIdx.x;
    int tid = threadIdx.x;
    int n = min(cnt[img], CAP);

    // ---- bitonic sort (descending) of N = next_pow2(n) keys ----
    int N = 1; while (N < n) N <<= 1;
    for (int i = tid; i < N; i += NBLK)
        keys[i] = (i < n) ? keys_g[(size_t)img * CAP + i] : 0ULL;
    __syncthreads();
    for (int k = 2; k <= N; k <<= 1) {
        for (int j = k >> 1; j > 0; j >>= 1) {
            for (int i = tid; i < N; i += NBLK) {
                int pp = i ^ j;
                if (pp > i) {
                    unsigned long long va = keys[i], vb = keys[pp];
                    bool desc = ((i & k) == 0);
                    if ((va < vb) == desc) { keys[i] = vb; keys[pp] = va; }
                }
            }
            __syncthreads();
        }
    }

    int m = min(n, TOPK_N);

    // ---- gather boxes for the top-m, xywh -> xyxy ----
    if (tid < m) {
        unsigned long long kk = keys[tid];
        unsigned a = 0xFFFFFFFFu - (unsigned)(kk & 0xFFFFFFFFu);
        float conf = __uint_as_float((unsigned)(kk >> 32));
        const float* p = pred + ((size_t)img * NA + a) * NCH;
        float x = p[0], y = p[1], w = p[2], h = p[3];
        bx1[tid] = x - w * 0.5f;
        by1[tid] = y - h * 0.5f;
        bx2[tid] = x + w * 0.5f;
        by2[tid] = y + h * 0.5f;
        bconf[tid] = conf;
    }
    __syncthreads();

    // ---- parallel suppression bit-matrix: word (i,w) covers j in [w*64, w*64+64) ----
    for (int idx = tid; idx < m * NWORDS; idx += NBLK) {
        int i = idx / NWORDS, w = idx % NWORDS;
        unsigned long long bits = 0ULL;
        int jlo = w * 64, jhi = min(jlo + 64, m);
        if (jhi > i + 1) {
            float ax1 = bx1[i], ay1 = by1[i], ax2 = bx2[i], ay2 = by2[i];
            float a1 = (ax2 - ax1) * (ay2 - ay1);
            for (int j = max(jlo, i + 1); j < jhi; ++j) {
                float ltx = fmaxf(ax1, bx1[j]);
                float lty = fmaxf(ay1, by1[j]);
                float rbx = fminf(ax2, bx2[j]);
                float rby = fminf(ay2, by2[j]);
                float ww = fmaxf(rbx - ltx, 0.0f);
                float hh = fmaxf(rby - lty, 0.0f);
                float inter = ww * hh;
                float a2 = (bx2[j] - bx1[j]) * (by2[j] - by1[j]);
                float iou = inter / (a1 + a2 - inter + 1e-9f);  // exact ref op order
                if (iou > IOU_T) bits |= 1ULL << (j - jlo);
            }
        }
        mask[i * NWORDS + w] = bits;
    }
    __syncthreads();

    // ---- serial greedy scan: single wave, bitmask registers, no block syncs ----
    if (tid < 64) {
        int lane = tid;
        unsigned long long kw = 0ULL;
        if (lane < NWORDS) {
            int rem = m - lane * 64;
            kw = (rem >= 64) ? ~0ULL : ((rem <= 0) ? 0ULL : ((1ULL << rem) - 1ULL));
        }
        for (int i = 0; i < m; ++i) {
            unsigned long long wi = __shfl(kw, i >> 6);        // broadcast owner's word
            if ((wi >> (i & 63)) & 1ULL) {                     // keep[i] still alive?
                unsigned long long mw = (lane < NWORDS) ? mask[i * NWORDS + lane] : 0ULL;
                kw &= ~mw;
            }
        }
        if (lane < NWORDS) keepw[lane] = kw;
    }
    __syncthreads();

    // ---- mean of kept confidences ----
    float s = 0.0f; int c = 0;
    if (tid < m) {
        if ((keepw[tid >> 6] >> (tid & 63)) & 1ULL) { s = bconf[tid]; c = 1; }
    }
    for (int off = 32; off > 0; off >>= 1) {
        s += __shfl_down(s, off);
        c += __shfl_down(c, off);
    }
    int wid = tid >> 6;
    if ((tid & 63) == 0) { rsum[wid] = s; rcnt[wid] = c; }
    __syncthreads();
    if (tid == 0) {
        float S = 0.0f; int C = 0;
        for (int wv = 0; wv < NBLK / 64; ++wv) { S += rsum[wv]; C += rcnt[wv]; }
        out[img] = (C > 0) ? S / (float)C : 0.0f;
    }
}

extern "C" void kernel_launch(void* const* d_in, const int* in_sizes, int n_in,
                              void* d_out, int out_size, void* d_ws, size_t ws_size,
                              hipStream_t stream) {
    const float* pred = (const float*)d_in[0];
    float* out = (float*)d_out;

    // ws layout: [0,64)   per-image counters (zeroed each launch by zero_cnt_kernel)
    //            [256,..) per-image key buffers (16 * 2048 * 8 B = 256 KB)
    int* cnt = (int*)d_ws;
    unsigned long long* keys = (unsigned long long*)((char*)d_ws + 256);

    zero_cnt_kernel<<<1, 64, 0, stream>>>(cnt);

    dim3 fgrid((NA + FBLK - 1) / FBLK, NIMG);
    filter_kernel<<<fgrid, FBLK, 0, stream>>>(pred, cnt, keys);
    nms_kernel<<<NIMG, NBLK, 0, stream>>>(pred, cnt, keys, out);
}